// Round 1
// baseline (375.263 us; speedup 1.0000x reference)
//
#include <hip/hip_runtime.h>

#define N_VERT 35709
#define N_FACE 70789
#define NB 32
#define M3 (3*N_VERT)   // 107127

// ---- workspace layout (float offsets) ----
#define WS_FS    ((size_t)0)                       // [32][107127] fs (uncentered), batch-major
#define WS_FN    (WS_FS + (size_t)NB*M3)           // [32][70789][3] face normals
#define WS_CPAD  (WS_FN + (size_t)NB*N_FACE*3)     // [32][256] padded coeff (cols 0..243, rest 0)
#define WS_ROT   (WS_CPAD + (size_t)NB*256)        // [32][9]  rot[c][j] (already transposed)
#define WS_TRE   (WS_ROT + (size_t)NB*9)           // [32][3]  trans - mean@rot
#define WS_G     (WS_TRE + (size_t)NB*3)           // [32][27] gamma + init_lit
#define WS_MEAN  (WS_G + (size_t)NB*27)            // [3]

// ---- output layout (float offsets) ----
#define FC_OFF   ((size_t)0)
#define LM_OFF   ((size_t)NB*M3)                   // 3428064
#define FST_OFF  (LM_OFF + (size_t)NB*68*2)        // 3432416

// ---- SH constants ----
#define A0C0 0.88622692545275801f
#define A1C1 1.77245385090551603f
#define A2C2 2.42703239430f
#define Y6C  0.70062393935f   // A2C2*0.5/sqrt(3)
#define Y8C  1.21351619715f   // A2C2*0.5

// ======================= Stage A: per-batch constants =======================
__global__ void __launch_bounds__(256) face3d_stageA(
    const float* __restrict__ coeff, const float* __restrict__ meanshape,
    float* __restrict__ ws) {
  __shared__ float red[3][256];
  int t = threadIdx.x;
  float s0=0.f, s1=0.f, s2=0.f;
  for (int v = t; v < N_VERT; v += 256) {
    s0 += meanshape[v*3+0];
    s1 += meanshape[v*3+1];
    s2 += meanshape[v*3+2];
  }
  red[0][t]=s0; red[1][t]=s1; red[2][t]=s2;
  __syncthreads();
  for (int off = 128; off > 0; off >>= 1) {
    if (t < off) {
      red[0][t]+=red[0][t+off];
      red[1][t]+=red[1][t+off];
      red[2][t]+=red[2][t+off];
    }
    __syncthreads();
  }
  float m0 = red[0][0]*(1.0f/N_VERT);
  float m1 = red[1][0]*(1.0f/N_VERT);
  float m2 = red[2][0]*(1.0f/N_VERT);
  if (t == 0) { ws[WS_MEAN]=m0; ws[WS_MEAN+1]=m1; ws[WS_MEAN+2]=m2; }

  // repack coeff cols 0..243 into 16B-aligned [32][256] (rest zero)
  for (int idx = t; idx < NB*256; idx += 256) {
    int b = idx >> 8, k = idx & 255;
    ws[WS_CPAD + idx] = (k < 244) ? coeff[b*277 + k] : 0.0f;
  }
  // g = gamma.reshape(3,9) + init_lit
  for (int idx = t; idx < NB*27; idx += 256) {
    int b = idx / 27, k = idx - b*27;
    ws[WS_G + idx] = coeff[b*277 + 247 + k] + (((k % 9) == 0) ? 0.8f : 0.0f);
  }
  if (t < NB) {
    int b = t;
    float ax = coeff[b*277+244], ay = coeff[b*277+245], az = coeff[b*277+246];
    float cx=cosf(ax), sx=sinf(ax);
    float cy=cosf(ay), sy=sinf(ay);
    float cz=cosf(az), sz=sinf(az);
    // T = Rz@Ry
    float T00=cz*cy, T01=-sz, T02=cz*sy;
    float T10=sz*cy, T11=cz,  T12=sz*sy;
    float T20=-sy,   T21=0.f, T22=cy;
    // R = T@Rx,  Rx = [[1,0,0],[0,cx,-sx],[0,sx,cx]]
    float R[3][3];
    R[0][0]=T00; R[0][1]=T01*cx+T02*sx; R[0][2]=-T01*sx+T02*cx;
    R[1][0]=T10; R[1][1]=T11*cx+T12*sx; R[1][2]=-T11*sx+T12*cx;
    R[2][0]=T20; R[2][1]=T21*cx+T22*sx; R[2][2]=-T21*sx+T22*cx;
    // rot = R^T : rot[c][j] = R[j][c]
    float rot[3][3];
    #pragma unroll
    for (int c=0;c<3;c++)
      #pragma unroll
      for (int j=0;j<3;j++)
        rot[c][j] = R[j][c];
    #pragma unroll
    for (int c=0;c<3;c++)
      #pragma unroll
      for (int j=0;j<3;j++)
        ws[WS_ROT + b*9 + c*3 + j] = rot[c][j];
    #pragma unroll
    for (int j=0;j<3;j++)
      ws[WS_TRE + b*3 + j] = coeff[b*277+274+j]
        - (m0*rot[0][j] + m1*rot[1][j] + m2*rot[2][j]);
  }
}

// ======================= Stage B: GEMMs =======================
#define FMA4(vv, cp, o) \
  acc[b] = fmaf((vv).x, (cp)[(o)+0], acc[b]); \
  acc[b] = fmaf((vv).y, (cp)[(o)+1], acc[b]); \
  acc[b] = fmaf((vv).z, (cp)[(o)+2], acc[b]); \
  acc[b] = fmaf((vv).w, (cp)[(o)+3], acc[b]);

template<int NCHUNK, int COFF, int TAIL>
__device__ __forceinline__ void gemmPhase(const float* __restrict__ Arow,
                                          const float* __restrict__ cpad,
                                          float acc[NB]) {
  const float4* __restrict__ A = (const float4*)Arow;
  float4 q0=A[0], q1=A[1], q2=A[2], q3=A[3];
  #pragma unroll 1
  for (int ch = 0; ch < NCHUNK; ++ch) {
    float4 c0=q0, c1=q1, c2=q2, c3=q3;
    if (ch + 1 < NCHUNK) {
      q0=A[(ch+1)*4+0]; q1=A[(ch+1)*4+1]; q2=A[(ch+1)*4+2]; q3=A[(ch+1)*4+3];
    } else if (TAIL) {
      q0=A[NCHUNK*4];
    }
    #pragma unroll
    for (int b = 0; b < NB; ++b) {
      const float* __restrict__ cp = cpad + b*256 + COFF + ch*16;
      FMA4(c0, cp, 0) FMA4(c1, cp, 4) FMA4(c2, cp, 8) FMA4(c3, cp, 12)
    }
  }
  if (TAIL) {
    #pragma unroll
    for (int b = 0; b < NB; ++b) {
      const float* __restrict__ cp = cpad + b*256 + COFF + NCHUNK*16;
      FMA4(q0, cp, 0)
    }
  }
}

__global__ void __launch_bounds__(256) face3d_stageB(
    const float* __restrict__ idB, const float* __restrict__ exB,
    const float* __restrict__ texB, const float* __restrict__ meanshape,
    const float* __restrict__ meantex, const float* __restrict__ cpad,
    float* __restrict__ fsOut, float* __restrict__ texOut) {
  int i = blockIdx.x*256 + threadIdx.x;
  if (i >= M3) return;
  float acc[NB];
  #pragma unroll
  for (int b=0;b<NB;b++) acc[b]=0.f;
  gemmPhase<5, 0,   0>(idB  + (size_t)i*80,  cpad, acc);   // id: K=80
  gemmPhase<4, 80,  0>(exB  + (size_t)i*64,  cpad, acc);   // ex: K=64
  float msv = meanshape[i];
  #pragma unroll
  for (int b=0;b<NB;b++) fsOut[(size_t)b*M3 + i] = acc[b] + msv;
  #pragma unroll
  for (int b=0;b<NB;b++) acc[b]=0.f;
  gemmPhase<6, 144, 1>(texB + (size_t)i*100, cpad, acc);   // tex: K=100 (6*16+4)
  float mtv = meantex[i];
  #pragma unroll
  for (int b=0;b<NB;b++) texOut[(size_t)b*M3 + i] = acc[b] + mtv;
}

// ======================= Stage C: face normals =======================
__global__ void __launch_bounds__(256) face3d_stageC(
    const int* __restrict__ face_buf, const float* __restrict__ fsAll,
    float* __restrict__ fnAll) {
  int bid = blockIdx.x;
  int b = bid & 31;
  int f = (bid >> 5)*256 + threadIdx.x;
  if (f >= N_FACE) return;
  const float* __restrict__ fs = fsAll + (size_t)b*M3;
  int i0 = face_buf[f*3+0];
  int i1 = face_buf[f*3+1];
  int i2 = face_buf[f*3+2];
  float v1x = fs[i0*3+0], v1y = fs[i0*3+1], v1z = fs[i0*3+2];
  float v2x = fs[i1*3+0], v2y = fs[i1*3+1], v2z = fs[i1*3+2];
  float v3x = fs[i2*3+0], v3y = fs[i2*3+1], v3z = fs[i2*3+2];
  float e1x = v1x-v2x, e1y = v1y-v2y, e1z = v1z-v2z;
  float e2x = v2x-v3x, e2y = v2y-v3y, e2z = v2z-v3z;
  float nx = e1y*e2z - e1z*e2y;
  float ny = e1z*e2x - e1x*e2z;
  float nz = e1x*e2y - e1y*e2x;
  float inv = 1.0f / fmaxf(sqrtf(nx*nx + ny*ny + nz*nz), 1e-12f);
  float* o = fnAll + ((size_t)b*N_FACE + f)*3;
  o[0] = nx*inv; o[1] = ny*inv; o[2] = nz*inv;
}

// ======================= Stage D: vertex normals + lighting + fst (+landmarks) =======================
__global__ void __launch_bounds__(256) face3d_stageD(
    const int* __restrict__ point_buf, const int* __restrict__ keypoints,
    const float* __restrict__ fsAll, const float* __restrict__ fnAll,
    const float* __restrict__ rotAll, const float* __restrict__ treAll,
    const float* __restrict__ gAll, float* __restrict__ out) {
  const int mainBlocks = NB*((N_VERT+255)/256);
  int bid = blockIdx.x;
  if (bid < mainBlocks) {
    int b = bid & 31;
    int v = (bid >> 5)*256 + threadIdx.x;
    if (v >= N_VERT) return;
    const float* __restrict__ fn = fnAll + (size_t)b*(3*N_FACE);
    float sx=0.f, sy=0.f, sz=0.f;
    #pragma unroll
    for (int j = 0; j < 8; ++j) {
      int f = point_buf[v*8+j];
      if (f < N_FACE) {           // index N_FACE == appended zero row
        const float* p = fn + (size_t)f*3;
        sx += p[0]; sy += p[1]; sz += p[2];
      }
    }
    float inv = 1.0f / fmaxf(sqrtf(sx*sx + sy*sy + sz*sz), 1e-12f);
    float n0 = sx*inv, n1 = sy*inv, n2 = sz*inv;
    const float* rot = rotAll + b*9;
    float r00=rot[0], r01=rot[1], r02=rot[2];
    float r10=rot[3], r11=rot[4], r12=rot[5];
    float r20=rot[6], r21=rot[7], r22=rot[8];
    float nx = n0*r00 + n1*r10 + n2*r20;
    float ny = n0*r01 + n1*r11 + n2*r21;
    float nz = n0*r02 + n1*r12 + n2*r22;
    float Y1 = -A1C1*ny;
    float Y2 =  A1C1*nz;
    float Y3 = -A1C1*nx;
    float Y4 =  A2C2*nx*ny;
    float Y5 = -A2C2*ny*nz;
    float Y6 =  Y6C*(3.f*nz*nz - 1.f);
    float Y7 = -A2C2*nx*nz;
    float Y8 =  Y8C*(nx*nx - ny*ny);
    const float* g = gAll + b*27;
    float L[3];
    #pragma unroll
    for (int c = 0; c < 3; ++c) {
      const float* gc = g + c*9;
      L[c] = A0C0*gc[0] + Y1*gc[1] + Y2*gc[2] + Y3*gc[3] + Y4*gc[4]
           + Y5*gc[5] + Y6*gc[6] + Y7*gc[7] + Y8*gc[8];
    }
    const float* fsv = fsAll + (size_t)b*M3 + (size_t)v*3;
    float f0 = fsv[0], f1 = fsv[1], f2 = fsv[2];
    const float* tre = treAll + b*3;
    float o0 = f0*r00 + f1*r10 + f2*r20 + tre[0];
    float o1 = f0*r01 + f1*r11 + f2*r21 + tre[1];
    float o2 = f0*r02 + f1*r12 + f2*r22 + tre[2];
    float* fst = out + FST_OFF + (size_t)b*M3 + (size_t)v*3;
    fst[0] = o0; fst[1] = o1; fst[2] = o2;
    float* fc = out + FC_OFF + (size_t)b*M3 + (size_t)v*3;  // holds tex from stage B
    fc[0] = fc[0]*L[0];
    fc[1] = fc[1]*L[1];
    fc[2] = fc[2]*L[2];
  } else {
    int idx = (bid - mainBlocks)*256 + threadIdx.x;
    if (idx >= NB*68) return;
    int b = idx / 68;
    int j = idx - b*68;
    int kp = keypoints[j];
    const float* rot = rotAll + b*9;
    const float* tre = treAll + b*3;
    const float* fsv = fsAll + (size_t)b*M3 + (size_t)kp*3;
    float f0 = fsv[0], f1 = fsv[1], f2 = fsv[2];
    float o0 = f0*rot[0] + f1*rot[3] + f2*rot[6] + tre[0];
    float o1 = f0*rot[1] + f1*rot[4] + f2*rot[7] + tre[1];
    float o2 = f0*rot[2] + f1*rot[5] + f2*rot[8] + tre[2];
    float zc = 10.0f - o2;
    float axv = 1015.0f*o0 + 112.0f*zc;
    float ayv = 1015.0f*o1 + 112.0f*zc;
    out[LM_OFF + (size_t)b*136 + (size_t)j*2 + 0] = axv/zc;
    out[LM_OFF + (size_t)b*136 + (size_t)j*2 + 1] = ayv/zc;
  }
}

// ======================= launch =======================
extern "C" void kernel_launch(void* const* d_in, const int* in_sizes, int n_in,
                              void* d_out, int out_size, void* d_ws, size_t ws_size,
                              hipStream_t stream) {
  const float* coeff     = (const float*)d_in[0];
  const float* idB       = (const float*)d_in[1];
  const float* exB       = (const float*)d_in[2];
  const float* texB      = (const float*)d_in[3];
  const float* meanshape = (const float*)d_in[4];
  const float* meantex   = (const float*)d_in[5];
  const int*   face_buf  = (const int*)d_in[6];
  const int*   point_buf = (const int*)d_in[7];
  const int*   keypoints = (const int*)d_in[8];
  float* out = (float*)d_out;
  float* ws  = (float*)d_ws;

  hipLaunchKernelGGL(face3d_stageA, dim3(1), dim3(256), 0, stream,
                     coeff, meanshape, ws);

  int gridB = (M3 + 255)/256;  // 419
  hipLaunchKernelGGL(face3d_stageB, dim3(gridB), dim3(256), 0, stream,
                     idB, exB, texB, meanshape, meantex,
                     ws + WS_CPAD, ws + WS_FS, out + FC_OFF);

  int gridC = NB * ((N_FACE + 255)/256);  // 32*277
  hipLaunchKernelGGL(face3d_stageC, dim3(gridC), dim3(256), 0, stream,
                     face_buf, ws + WS_FS, ws + WS_FN);

  int mainBlocks = NB * ((N_VERT + 255)/256);      // 4480
  int lmBlocks   = (NB*68 + 255)/256;              // 9
  hipLaunchKernelGGL(face3d_stageD, dim3(mainBlocks + lmBlocks), dim3(256), 0, stream,
                     point_buf, keypoints, ws + WS_FS, ws + WS_FN,
                     ws + WS_ROT, ws + WS_TRE, ws + WS_G, out);
}